// Round 6
// baseline (1072.153 us; speedup 1.0000x reference)
//
#include <hip/hip_runtime.h>
#include <hip/hip_bf16.h>
#include <cstdint>
#include <cstddef>

typedef __attribute__((ext_vector_type(8))) short short8;   // 8 bf16 = 4 VGPRs (MFMA A/B frag)
typedef __attribute__((ext_vector_type(4))) float f32x4;    // MFMA C/D frag (also nt-load vec)

__device__ __forceinline__ unsigned short f2bf(float f) {
  unsigned u = __float_as_uint(f);
  unsigned r = (u + 0x7fffu + ((u >> 16) & 1u)) >> 16;   // RNE
  return (unsigned short)r;
}
__device__ __forceinline__ float bf2f(unsigned short b) {
  return __uint_as_float(((unsigned)b) << 16);
}
// order-preserving float -> uint key for atomicMax (0 sentinel < every real key)
__device__ __forceinline__ unsigned fkey(float f) {
  unsigned b = __float_as_uint(f);
  return (b & 0x80000000u) ? ~b : (b | 0x80000000u);
}

// ---------------------------------------------------------------------------
// Pack W1a [256(k) x 256(col)] fp32 -> bf16 in MFMA-B-fragment order:
// packedB[((s*32 + kk*4+quad)*64 + n)*8 + j] = bf16(W1a[kk*32+quad*8+j][s*64+n])
// (s = col>>6 stage, n = col&63). A lane's b-frag is one contiguous 16B read.
// ---------------------------------------------------------------------------
__global__ __launch_bounds__(256)
void prep_b_kernel(const float* __restrict__ W1a, unsigned short* __restrict__ packedB) {
  int idx = blockIdx.x * 256 + threadIdx.x;   // 0..65535
  int j  = idx & 7;
  int n  = (idx >> 3) & 63;
  int kq = (idx >> 9) & 31;                   // kk*4 + quad
  int s  = idx >> 14;                         // column stage (64 cols each)
  int k  = (kq >> 2) * 32 + (kq & 3) * 8 + j;
  int col = s * 64 + n;
  packedB[idx] = f2bf(W1a[k * 256 + col]);
}

// score epilogue: fold acc -> partial attention score, reduce over 16 lanes (m)
__device__ __forceinline__ void score_store(const f32x4 acc[4], const float b1r[4],
                                            const float w2r[4], float* dst,
                                            int m, int quad) {
  float p[4];
  #pragma unroll
  for (int r = 0; r < 4; ++r) {
    float s = 0.f;
    #pragma unroll
    for (int nb = 0; nb < 4; ++nb)
      s += fmaxf(acc[nb][r] + b1r[nb], 0.f) * w2r[nb];
    p[r] = s;
  }
  #pragma unroll
  for (int off = 1; off < 16; off <<= 1) {
    #pragma unroll
    for (int r = 0; r < 4; ++r) p[r] += __shfl_xor(p[r], off, 64);
  }
  if (m == 0) {
    #pragma unroll
    for (int r = 0; r < 4; ++r) dst[quad * 4 + r] = p[r];
  }
}

// ---------------------------------------------------------------------------
// Fused phase-A, 8-wave blocks. Wave (cg, ns): cg = chan group (64 hidden cols),
// ns = node half (32 nodes). B streamed from L2 (no resident frags -> lower
// VGPRs -> 4 waves/SIMD target). Pooling scan is branchless per-run, depth
// 32/wave; run boundaries found once per tile by wave 0 via ballot. Every
// nonempty run-intersection is flushed DIRECTLY via atomics (sum/max are
// associative, so a run split across the two node-halves contributes via two
// atomics -- no cross-wave merge handoff, no race surface). Contiguous tile
// chunks per block for atomic/L2 locality. x loads are non-temporal.
// ---------------------------------------------------------------------------
__global__ __launch_bounds__(512, 4)
void phase_a_kernel(const float* __restrict__ x, const int* __restrict__ batch,
                    const unsigned short* __restrict__ packedB,
                    const float* __restrict__ b1a, const float* __restrict__ W2a,
                    const float* __restrict__ b2a,
                    float* __restrict__ attbuf, float* __restrict__ sumbuf,
                    unsigned* __restrict__ maxkey, float* __restrict__ cntbuf,
                    int nnodes, int ntiles, int tpb) {
  __shared__ __align__(16) unsigned short sX[64][264];   // bf16 x tile, +8 pad/row
  __shared__ float sScoreP[4][64];                       // per-chan-group score partials
  __shared__ float sAw[64];
  __shared__ int   sBatch[64];
  __shared__ int   sRunStart[65];                        // run starts + sentinel
  __shared__ int   sSeg[64];                             // seg id per run
  __shared__ int   sNruns;

  const int t = threadIdx.x;
  const int lane = t & 63;
  const int wv = t >> 6;          // 0..7
  const int cg = wv & 3;          // channel group: hidden cols [cg*64, cg*64+64)
  const int ns = wv >> 2;         // node half: nodes [ns*32, ns*32+32)
  const int m = lane & 15;
  const int quad = lane >> 4;
  const int chan = cg * 64 + lane;   // channel owned in the pooling scan

  float b1r[4], w2r[4];
  #pragma unroll
  for (int nb = 0; nb < 4; ++nb) {
    int col = cg * 64 + nb * 16 + m;
    b1r[nb] = b1a[col];
    w2r[nb] = W2a[col];
  }
  const float b2 = b2a[0];

  // per-lane base into packedB; frag (kk,nb) at +kk*2048 + nb*128 elements
  const unsigned short* Bbase = packedB + (size_t)((cg * 32 + quad) * 64 + m) * 8;

  const int tile0 = blockIdx.x * tpb;
  const int tile1 = min(ntiles, tile0 + tpb);
  for (int tile = tile0; tile < tile1; ++tile) {
    const int block0 = tile * 64;
    const int nvalid = min(64, nnodes - block0);

    if (t < 64) sBatch[t] = (t < nvalid) ? batch[block0 + t] : -1;

    // stage x tile (64 x 256 fp32) -> bf16 LDS, coalesced nontemporal float4
    #pragma unroll
    for (int it = 0; it < 8; ++it) {
      int idx = it * 512 + t;       // float4 slot 0..4095
      int row = idx >> 6;           // = it*8 + wv
      int c4  = idx & 63;
      f32x4 v = {0.f, 0.f, 0.f, 0.f};
      if (block0 + row < nnodes)
        v = __builtin_nontemporal_load(
              reinterpret_cast<const f32x4*>(x) + (size_t)(block0 + row) * 64 + c4);
      ushort4 h;
      h.x = f2bf(v.x); h.y = f2bf(v.y); h.z = f2bf(v.z); h.w = f2bf(v.w);
      *reinterpret_cast<ushort4*>(&sX[row][c4 * 4]) = h;
    }
    __syncthreads();   // (1) tile staged

    // GEMM: wave (cg,ns) computes h for nodes [ns*32,ns*32+32), cols cg*64..+63
    {
      f32x4 acc0[4] = {{0,0,0,0},{0,0,0,0},{0,0,0,0},{0,0,0,0}};
      f32x4 acc1[4] = {{0,0,0,0},{0,0,0,0},{0,0,0,0},{0,0,0,0}};
      const int mt0 = ns * 2, mt1 = ns * 2 + 1;
      #pragma unroll
      for (int kk = 0; kk < 8; ++kk) {
        short8 Bt[4];
        #pragma unroll
        for (int nb = 0; nb < 4; ++nb)
          Bt[nb] = *reinterpret_cast<const short8*>(Bbase + kk * 2048 + nb * 128);
        short8 a0 = *reinterpret_cast<const short8*>(&sX[mt0 * 16 + m][kk * 32 + quad * 8]);
        short8 a1 = *reinterpret_cast<const short8*>(&sX[mt1 * 16 + m][kk * 32 + quad * 8]);
        #pragma unroll
        for (int nb = 0; nb < 4; ++nb) {
          acc0[nb] = __builtin_amdgcn_mfma_f32_16x16x32_bf16(a0, Bt[nb], acc0[nb], 0, 0, 0);
          acc1[nb] = __builtin_amdgcn_mfma_f32_16x16x32_bf16(a1, Bt[nb], acc1[nb], 0, 0, 0);
        }
      }
      score_store(acc0, b1r, w2r, &sScoreP[cg][mt0 * 16], m, quad);
      score_store(acc1, b1r, w2r, &sScoreP[cg][mt1 * 16], m, quad);
    }
    __syncthreads();   // (2) score partials ready

    if (t < 64) {   // wave 0 exactly
      float s = sScoreP[0][t] + sScoreP[1][t] + sScoreP[2][t] + sScoreP[3][t] + b2;
      sAw[t] = 1.f / (1.f + __expf(-s));

      // run structure via ballot over sorted batch ids
      int b = sBatch[t];
      bool valid = t < nvalid;
      bool isStart = valid && (t == 0 || sBatch[t - 1] != b);
      unsigned long long mask = __ballot(isStart);
      if (isStart) {
        int rid = __popcll(mask & ((1ull << t) - 1ull));
        sRunStart[rid] = t;
        sSeg[rid] = b;
        unsigned long long rest = (t < 63) ? (mask >> (t + 1)) : 0ull;
        int nxt = rest ? (t + __ffsll((long long)rest)) : nvalid;   // next start or end
        atomicAdd(&cntbuf[b], (float)(nxt - t));                    // exact run length
      }
      if (t == 0) { int nr = __popcll(mask); sNruns = nr; sRunStart[nr] = nvalid; }
    }
    __syncthreads();   // (3) aw + run table ready

    // branchless per-run pooling scan; wave (cg,ns) covers its 64 chans x 32
    // nodes; every nonempty run-intersection flushed directly (associative ops)
    {
      const int lo0 = ns * 32;
      const int hi0 = min(ns * 32 + 32, nvalid);
      const int nr = sNruns;
      for (int r = 0; r < nr; ++r) {
        int rs = sRunStart[r];
        int re = sRunStart[r + 1];
        int lo = max(rs, lo0), hi = min(re, hi0);
        if (lo >= hi) continue;                    // wave-uniform
        float aS = 0.f, aA = 0.f, aM = -INFINITY;
        for (int i = lo; i < hi; ++i) {
          float xv = bf2f(sX[i][chan]);
          float awv = sAw[i];                      // broadcast read
          aS += xv;
          aA = fmaf(xv, awv, aA);
          aM = fmaxf(aM, xv);
        }
        int seg = sSeg[r];
        atomicAdd(&sumbuf[(size_t)seg * 256 + chan], aS);
        atomicAdd(&attbuf[(size_t)seg * 256 + chan], aA);
        atomicMax(&maxkey[(size_t)seg * 256 + chan], fkey(aM));
      }
    }
    __syncthreads();   // (4) protect sX + run table before next tile's staging
  }
}

// ---------------------------------------------------------------------------
// Final MLP: out[g] = relu(comb[g] @ W1f + b1f) @ W2f + b2f, 4 graphs/block
// (1024 blocks -> good latency hiding), rank-1-update formulation.
// ---------------------------------------------------------------------------
__global__ __launch_bounds__(256, 4)
void final_mlp_kernel(const float* __restrict__ attbuf, const float* __restrict__ sumbuf,
                      const unsigned* __restrict__ maxkey, const float* __restrict__ cntbuf,
                      const float* __restrict__ W1f, const float* __restrict__ b1f,
                      const float* __restrict__ W2f, const float* __restrict__ b2f,
                      float* __restrict__ out) {
  __shared__ float sComb[4 * 768];
  __shared__ float sHid[4 * 256];
  const int t = threadIdx.x;
  const int g0 = blockIdx.x * 4;

  for (int idx = t; idx < 4 * 768; idx += 256) {
    int g = idx / 768;
    int k = idx - g * 768;
    int gg = g0 + g;
    float cnt = cntbuf[gg];
    float v;
    if (k < 256) {
      v = attbuf[(size_t)gg * 256 + k];
    } else if (k < 512) {
      v = sumbuf[(size_t)gg * 256 + (k - 256)] / fmaxf(cnt, 1.f);
    } else {
      unsigned u = maxkey[(size_t)gg * 256 + (k - 512)];
      unsigned b = (u & 0x80000000u) ? (u & 0x7fffffffu) : ~u;
      v = (cnt > 0.f) ? __uint_as_float(b) : 0.f;   // empty segment -> 0
    }
    sComb[idx] = v;
  }
  __syncthreads();

  float acc[4] = {0, 0, 0, 0};
  #pragma unroll 4
  for (int k = 0; k < 768; ++k) {
    float wv = W1f[k * 256 + t];
    #pragma unroll
    for (int g = 0; g < 4; ++g) acc[g] = fmaf(sComb[g * 768 + k], wv, acc[g]);
  }
  float bb = b1f[t];
  #pragma unroll
  for (int g = 0; g < 4; ++g) sHid[g * 256 + t] = fmaxf(acc[g] + bb, 0.f);
  __syncthreads();

  float acc2[4] = {0, 0, 0, 0};
  #pragma unroll 4
  for (int k = 0; k < 256; ++k) {
    float wv = W2f[k * 256 + t];
    #pragma unroll
    for (int g = 0; g < 4; ++g) acc2[g] = fmaf(sHid[g * 256 + k], wv, acc2[g]);
  }
  float bo = b2f[t];
  #pragma unroll
  for (int g = 0; g < 4; ++g) out[(size_t)(g0 + g) * 256 + t] = acc2[g] + bo;
}

// ---------------------------------------------------------------------------
extern "C" void kernel_launch(void* const* d_in, const int* in_sizes, int n_in,
                              void* d_out, int out_size, void* d_ws, size_t ws_size,
                              hipStream_t stream) {
  const float* x   = (const float*)d_in[0];
  const int* batch = (const int*)d_in[1];
  const float* W1a = (const float*)d_in[2];
  const float* b1a = (const float*)d_in[3];
  const float* W2a = (const float*)d_in[4];
  const float* b2a = (const float*)d_in[5];
  const float* W1f = (const float*)d_in[6];
  const float* b1f = (const float*)d_in[7];
  const float* W2f = (const float*)d_in[8];
  const float* b2f = (const float*)d_in[9];
  float* out = (float*)d_out;

  const int N = in_sizes[0] / 256;
  const int G = out_size / 256;

  char* ws = (char*)d_ws;
  float* attbuf = (float*)ws;
  float* sumbuf = attbuf + (size_t)G * 256;
  unsigned* maxkey = (unsigned*)(sumbuf + (size_t)G * 256);
  float* cntbuf = (float*)(maxkey + (size_t)G * 256);
  unsigned short* packedB = (unsigned short*)(cntbuf + G);

  size_t zero_bytes = ((size_t)G * 256 * 3 + G) * sizeof(float);
  (void)hipMemsetAsync(d_ws, 0, zero_bytes, stream);

  prep_b_kernel<<<256, 256, 0, stream>>>(W1a, packedB);

  int ntiles = (N + 63) / 64;
  const int nblocks = 512;
  int tpb = (ntiles + nblocks - 1) / nblocks;
  phase_a_kernel<<<nblocks, 512, 0, stream>>>(x, batch, packedB, b1a, W2a, b2a,
                                              attbuf, sumbuf, maxkey, cntbuf,
                                              N, ntiles, tpb);

  final_mlp_kernel<<<G / 4, 256, 0, stream>>>(attbuf, sumbuf, maxkey, cntbuf,
                                              W1f, b1f, W2f, b2f, out);
}